// Round 11
// baseline (162.373 us; speedup 1.0000x reference)
//
#include <hip/hip_runtime.h>

#define PP 50
#define TPB1 256                 // K1 block size
#define TPBS 320                 // sweep kernels: 4 compute waves + 1 readback wave
#define NBATCH 2048
#define GB 4                     // batches per block in sweep kernels
#define NBLK 512                 // sweep grid: all co-resident (2 blocks/CU)
#define NBLK1 512                // K1 grid (4 batches/block, wave=batch)

static constexpr float EPSF = 1e-5f;
static constexpr double INV_ETOT = 1.0 / 5120000.0;   // 1/(B*P*P)

static __device__ __forceinline__ float lrelu(float x) {
    return fmaxf(x, 0.0f) + 0.01f * fminf(x, 0.0f);
}
static __device__ __forceinline__ float rfl(float x) {
    return __int_as_float(__builtin_amdgcn_readfirstlane(__float_as_int(x)));
}

// d_ws layout (doubles; no zero-init needed — every slot stored every launch):
//   [0, 5120)        pacc1[10][512]  BN1 partials (sum 0-4, sumsq 5-9)
//   [5120, 10240)    pacc2[10][512]  BN2 partials
//   [10240, +40B)    fold1[10] (floats): sc1[5], sh1[5] published by K2 block 0
#define PACC2_OFF 5120
#define FOLD1_OFF 10240

// ==== K1: BN1 stats via separable per-node sums (d_ij = z_i * w_j) =========
__global__ __launch_bounds__(TPB1) void stats1_kernel(
    const float* __restrict__ feat, const float* __restrict__ ang,
    const float* __restrict__ W1, const float* __restrict__ b1,
    double* __restrict__ ws)
{
    __shared__ double bacc[4][10];
    const int t = threadIdx.x;
    const int lane = t & 63;
    const int wv = t >> 6;

    float v0[5], v1[5], v2[5], v3[5], bb1[5];
#pragma unroll
    for (int o = 0; o < 5; ++o) {
        v0[o] = rfl(W1[o*5+0] - W1[o*5+2]);
        v1[o] = rfl(W1[o*5+1] + W1[o*5+2]);
        v2[o] = rfl(W1[o*5+3]);
        v3[o] = rfl(W1[o*5+4]);
        bb1[o] = rfl(b1[o]);
    }

    float f = 0.f, zr = 0.f, zi = 0.f, inv = 0.f;
    if (lane < PP) {
        const int idx = (blockIdx.x * 4 + wv) * PP + lane;
        f = feat[idx];
        float2 a2 = ((const float2*)ang)[idx];
        zr = a2.x; zi = a2.y;
        inv = 1.0f / (zr*zr + zi*zi);
    }
    const float wr = zr * inv, wi = -zi * inv;   // lanes >=50: all zero

    float p[16] = { f, f*f, zr, zi, wr, wi, f*zr, f*zi, f*wr, f*wi,
                    zr*zr, zi*zi, zr*zi, wr*wr, wi*wi, wr*wi };
#pragma unroll
    for (int k = 0; k < 16; ++k) {
        float v = p[k];
#pragma unroll
        for (int off = 32; off > 0; off >>= 1) v += __shfl_down(v, off, 64);
        p[k] = v;
    }
    if (lane == 0) {
        const double P0 = p[0], P1 = p[1], P2 = p[2], P3 = p[3], P4 = p[4];
        const double P5 = p[5], P6 = p[6], P7 = p[7], P8 = p[8], P9 = p[9];
        const double P10 = p[10], P11 = p[11], P12 = p[12];
        const double P13 = p[13], P14 = p[14], P15 = p[15];
        const double Sfi = 50.0 * P0;
        const double Sdr = P2*P4 - P3*P5;
        const double Sdi = P3*P4 + P2*P5;
        const double m00 = 50.0 * P1, m11 = m00, m01 = P0*P0;
        const double m02 = P6*P4 - P7*P5;
        const double m03 = P7*P4 + P6*P5;
        const double m12 = P2*P8 - P3*P9;
        const double m13 = P3*P8 + P2*P9;
        const double m22 = P10*P13 - 2.0*P12*P15 + P11*P14;
        const double m33 = P11*P13 + 2.0*P12*P15 + P10*P14;
        const double m23 = P12*P13 + P10*P15 - P11*P15 - P12*P14;
#pragma unroll
        for (int o = 0; o < 5; ++o) {
            const double a0=v0[o], a1=v1[o], a2=v2[o], a3=v3[o], bo=bb1[o];
            const double sy = a0*Sfi + a1*Sfi + a2*Sdr + a3*Sdi + 2500.0*bo;
            const double q  = a0*a0*m00 + a1*a1*m11 + a2*a2*m22 + a3*a3*m33
                           + 2.0*(a0*a1*m01 + a0*a2*m02 + a0*a3*m03
                                + a1*a2*m12 + a1*a3*m13 + a2*a3*m23);
            bacc[wv][o]   = sy;
            bacc[wv][5+o] = q + 2.0*bo*sy - 2500.0*bo*bo;
        }
    }
    __syncthreads();
    if (t < 10) {
        ws[t * NBLK1 + blockIdx.x] =
            bacc[0][t] + bacc[1][t] + bacc[2][t] + bacc[3][t];
    }
}

// ==== K2: edge sweep -> BN2 partials. Waves 0-3 compute, wave 4 readback ===
__global__ __launch_bounds__(TPBS, 3) void pass2_kernel(
    const float* __restrict__ feat, const float* __restrict__ ang,
    const float* __restrict__ W1, const float* __restrict__ b1,
    const float* __restrict__ g1, const float* __restrict__ bt1,
    const float* __restrict__ W2, const float* __restrict__ b2,
    double* __restrict__ ws)
{
    __shared__ float4 snd[GB * PP];
    __shared__ double tmp[10];
    __shared__ float red[5][10];
    const int t = threadIdx.x;
    const int lane = t & 63;
    const int wv = t >> 6;

    if (t < GB * PP) {
        const int idx = blockIdx.x * (GB * PP) + t;   // fully coalesced
        float f = feat[idx];
        float2 a2 = ((const float2*)ang)[idx];
        snd[t] = make_float4(f, a2.x, a2.y, 1.0f / (a2.x*a2.x + a2.y*a2.y));
    } else if (t >= 256) {
        // wave 4: lane-parallel BN1 partial readback + f64 butterfly
#pragma unroll
        for (int s = 0; s < 10; ++s) {
            double v = 0.0;
#pragma unroll
            for (int k = 0; k < NBLK1 / 64; ++k)
                v += ws[s * NBLK1 + lane + 64 * k];
#pragma unroll
            for (int off = 32; off > 0; off >>= 1) v += __shfl_xor(v, off, 64);
            if (lane == 0) tmp[s] = v;
        }
    }

    float v0[5], v1[5], v2[5], v3[5], bb1[5], w2[25], bb2[5];
#pragma unroll
    for (int o = 0; o < 5; ++o) {
        v0[o] = rfl(W1[o*5+0] - W1[o*5+2]);
        v1[o] = rfl(W1[o*5+1] + W1[o*5+2]);
        v2[o] = rfl(W1[o*5+3]);
        v3[o] = rfl(W1[o*5+4]);
        bb1[o] = rfl(b1[o]); bb2[o] = rfl(b2[o]);
    }
#pragma unroll
    for (int i = 0; i < 25; ++i) w2[i] = rfl(W2[i]);

    __syncthreads();

    float sc1[5], sh1[5];
#pragma unroll
    for (int o = 0; o < 5; ++o) {
        double mu  = tmp[o]   * INV_ETOT;
        double var = tmp[5+o] * INV_ETOT - mu * mu;
        float sc = rfl(g1[o]) * rsqrtf((float)var + EPSF);
        sc1[o] = rfl(sc);
        sh1[o] = rfl(rfl(bt1[o]) - (float)mu * sc);
    }
    if (blockIdx.x == 0 && t == 0) {
        float* fold1 = (float*)(ws + FOLD1_OFF);
#pragma unroll
        for (int o = 0; o < 5; ++o) { fold1[o] = sc1[o]; fold1[5+o] = sh1[o]; }
    }

    float a[10];
#pragma unroll
    for (int k = 0; k < 10; ++k) a[k] = 0.f;

    if (t < 250) {
        const int pi = t / 5;
        const int s5 = t - pi*5;
#pragma unroll 1
        for (int g = 0; g < GB; ++g) {
            const float4 ni = snd[g*PP + pi];
            const float fi = ni.x, ari = ni.y, aii = ni.z;
            float4 njs[10];
#pragma unroll
            for (int q = 0; q < 10; ++q) njs[q] = snd[g*PP + s5*10 + q];
#pragma unroll
            for (int q = 0; q < 10; ++q) {
                const float4 nj = njs[q];
                const float dr = fmaf(ari, nj.y,  aii*nj.z) * nj.w;
                const float di = fmaf(aii, nj.y, -ari*nj.z) * nj.w;
                float h1[5];
#pragma unroll
                for (int o = 0; o < 5; ++o) {
                    float y = fmaf(v0[o], fi, fmaf(v1[o], nj.x,
                              fmaf(v2[o], dr, fmaf(v3[o], di, bb1[o]))));
                    h1[o] = lrelu(fmaf(y, sc1[o], sh1[o]));
                }
#pragma unroll
                for (int o = 0; o < 5; ++o) {
                    float y = bb2[o];
                    y = fmaf(w2[o*5+0], h1[0], y);
                    y = fmaf(w2[o*5+1], h1[1], y);
                    y = fmaf(w2[o*5+2], h1[2], y);
                    y = fmaf(w2[o*5+3], h1[3], y);
                    y = fmaf(w2[o*5+4], h1[4], y);
                    a[o]   += y;
                    a[5+o]  = fmaf(y, y, a[5+o]);
                }
            }
        }
    }

#pragma unroll
    for (int k = 0; k < 10; ++k) {
        float v = a[k];
#pragma unroll
        for (int off = 32; off > 0; off >>= 1) v += __shfl_down(v, off, 64);
        a[k] = v;
    }
    if (lane == 0) {
#pragma unroll
        for (int k = 0; k < 10; ++k) red[wv][k] = a[k];
    }
    __syncthreads();
    if (t < 10) {
        ws[PACC2_OFF + t * NBLK + blockIdx.x] =
            (double)(red[0][t] + red[1][t] + red[2][t] + red[3][t] + red[4][t]);
    }
}

// ==== K3: full MLP, mean per dst, rotate, write. Wave 4 = BN2 readback =====
__global__ __launch_bounds__(TPBS, 3) void pass3_kernel(
    const float* __restrict__ pt,
    const float* __restrict__ feat, const float* __restrict__ ang,
    const float* __restrict__ W1, const float* __restrict__ b1,
    const float* __restrict__ g2, const float* __restrict__ bt2,
    const float* __restrict__ W2, const float* __restrict__ b2,
    const float* __restrict__ W3, const float* __restrict__ b3,
    const double* __restrict__ ws, float* __restrict__ out)
{
    __shared__ float4 snd[GB * PP];
    __shared__ float spt[GB * PP];
    __shared__ double tmp[10];
    __shared__ float part[GB][250][5];      // 20 KB
    const int t = threadIdx.x;
    const int lane = t & 63;

    if (t < GB * PP) {
        const int idx = blockIdx.x * (GB * PP) + t;
        float f = feat[idx];
        float2 a2 = ((const float2*)ang)[idx];
        snd[t] = make_float4(f, a2.x, a2.y, 1.0f / (a2.x*a2.x + a2.y*a2.y));
        spt[t] = pt[idx];
    } else if (t >= 256) {
        // wave 4: lane-parallel BN2 partial readback + f64 butterfly
#pragma unroll
        for (int s = 0; s < 10; ++s) {
            double v = 0.0;
#pragma unroll
            for (int k = 0; k < NBLK / 64; ++k)
                v += ws[PACC2_OFF + s * NBLK + lane + 64 * k];
#pragma unroll
            for (int off = 32; off > 0; off >>= 1) v += __shfl_xor(v, off, 64);
            if (lane == 0) tmp[s] = v;
        }
    }

    float v0[5], v1[5], v2[5], v3[5], bb1[5], w2[25], bb2[5], w3[25], bb3[5];
#pragma unroll
    for (int o = 0; o < 5; ++o) {
        v0[o] = rfl(W1[o*5+0] - W1[o*5+2]);
        v1[o] = rfl(W1[o*5+1] + W1[o*5+2]);
        v2[o] = rfl(W1[o*5+3]);
        v3[o] = rfl(W1[o*5+4]);
        bb1[o] = rfl(b1[o]); bb2[o] = rfl(b2[o]); bb3[o] = rfl(b3[o]);
    }
#pragma unroll
    for (int i = 0; i < 25; ++i) { w2[i] = rfl(W2[i]); w3[i] = rfl(W3[i]); }

    const float* fold1 = (const float*)(ws + FOLD1_OFF);
    float sc1[5], sh1[5];
#pragma unroll
    for (int o = 0; o < 5; ++o) { sc1[o] = rfl(fold1[o]); sh1[o] = rfl(fold1[5+o]); }

    __syncthreads();

    float sc2[5], sh2[5];
#pragma unroll
    for (int o = 0; o < 5; ++o) {
        double mu2  = tmp[o]   * INV_ETOT;
        double var2 = tmp[5+o] * INV_ETOT - mu2 * mu2;
        float s2 = rfl(g2[o]) * rsqrtf((float)var2 + EPSF);
        sc2[o] = rfl(s2);
        sh2[o] = rfl(rfl(bt2[o]) - (float)mu2 * s2);
    }

    if (t < 250) {
        const int pi = t / 5;
        const int s5 = t - pi*5;
#pragma unroll 1
        for (int g = 0; g < GB; ++g) {
            float a[5] = {0.f, 0.f, 0.f, 0.f, 0.f};
            const float4 ni = snd[g*PP + pi];
            const float fi = ni.x, ari = ni.y, aii = ni.z;
            float4 njs[10];
#pragma unroll
            for (int q = 0; q < 10; ++q) njs[q] = snd[g*PP + s5*10 + q];
#pragma unroll
            for (int q = 0; q < 10; ++q) {
                const float4 nj = njs[q];
                const float dr = fmaf(ari, nj.y,  aii*nj.z) * nj.w;
                const float di = fmaf(aii, nj.y, -ari*nj.z) * nj.w;
                float h1[5], h2[5];
#pragma unroll
                for (int o = 0; o < 5; ++o) {
                    float y = fmaf(v0[o], fi, fmaf(v1[o], nj.x,
                              fmaf(v2[o], dr, fmaf(v3[o], di, bb1[o]))));
                    h1[o] = lrelu(fmaf(y, sc1[o], sh1[o]));
                }
#pragma unroll
                for (int o = 0; o < 5; ++o) {
                    float y = bb2[o];
                    y = fmaf(w2[o*5+0], h1[0], y);
                    y = fmaf(w2[o*5+1], h1[1], y);
                    y = fmaf(w2[o*5+2], h1[2], y);
                    y = fmaf(w2[o*5+3], h1[3], y);
                    y = fmaf(w2[o*5+4], h1[4], y);
                    h2[o] = lrelu(fmaf(y, sc2[o], sh2[o]));
                }
#pragma unroll
                for (int o = 0; o < 5; ++o) {
                    float y = bb3[o];
                    y = fmaf(w3[o*5+0], h2[0], y);
                    y = fmaf(w3[o*5+1], h2[1], y);
                    y = fmaf(w3[o*5+2], h2[2], y);
                    y = fmaf(w3[o*5+3], h2[3], y);
                    y = fmaf(w3[o*5+4], h2[4], y);
                    a[o] += y;
                }
            }
#pragma unroll
            for (int c = 0; c < 5; ++c) part[g][t][c] = a[c];
        }
    }
    __syncthreads();   // single sync after all partials stored

    if (t < GB * PP) {
        const int g  = t / PP;
        const int pi = t - g * PP;
        float m[5];
#pragma unroll
        for (int c = 0; c < 5; ++c) {
            m[c] = (part[g][5*pi][c] + part[g][5*pi+1][c] + part[g][5*pi+2][c] +
                    part[g][5*pi+3][c] + part[g][5*pi+4][c]) * 0.02f;
        }
        const int d = blockIdx.x * (GB * PP) + t;
        const float4 ni = snd[t];
        float ss, cc;
        sincosf(6.2831853071795865f * m[4], &ss, &cc);
        float* o = out + (size_t)d * 7;
        o[0] = spt[t];
        o[1] = m[0];
        o[2] = m[1];
        o[3] = m[2];
        o[4] = m[3];
        o[5] = cc * ni.y - ss * ni.z;
        o[6] = cc * ni.z + ss * ni.y;
    }
}

extern "C" void kernel_launch(void* const* d_in, const int* in_sizes, int n_in,
                              void* d_out, int out_size, void* d_ws, size_t ws_size,
                              hipStream_t stream)
{
    const float* pt   = (const float*)d_in[0];
    const float* feat = (const float*)d_in[1];
    const float* ang  = (const float*)d_in[2];
    const float* W1   = (const float*)d_in[3];
    const float* b1   = (const float*)d_in[4];
    const float* g1   = (const float*)d_in[5];
    const float* bt1  = (const float*)d_in[6];
    const float* W2   = (const float*)d_in[7];
    const float* b2   = (const float*)d_in[8];
    const float* g2   = (const float*)d_in[9];
    const float* bt2  = (const float*)d_in[10];
    const float* W3   = (const float*)d_in[11];
    const float* b3   = (const float*)d_in[12];
    // d_in[13] = edge_index: closed-form structure (dst=b*P+pi, src=b*P+pj), unused
    float* out = (float*)d_out;
    double* ws = (double*)d_ws;

    // 3 dispatches, no memset: every ws slot is stored before it is read
    stats1_kernel<<<NBLK1, TPB1, 0, stream>>>(feat, ang, W1, b1, ws);
    pass2_kernel<<<NBLK, TPBS, 0, stream>>>(feat, ang, W1, b1, g1, bt1, W2, b2, ws);
    pass3_kernel<<<NBLK, TPBS, 0, stream>>>(pt, feat, ang, W1, b1,
                                            g2, bt2, W2, b2, W3, b3, ws, out);
}

// Round 12
// 144.215 us; speedup vs baseline: 1.1259x; 1.1259x over previous
//
#include <hip/hip_runtime.h>

#define PP 50
#define TPB 256
#define NBATCH 2048
#define GB 2                     // batches per block in edge-sweep kernels
#define NBLK2 (NBATCH / GB)      // 1024 blocks for K2/K3
#define NBLK1 512                // K1: 4 batches/block, 1 wave each
#define NCOPY 64                 // contention-spreading copies for stat atomics

static constexpr float EPSF = 1e-5f;
static constexpr double INV_ETOT = 1.0 / 5120000.0;   // 1/(B*P*P)

static __device__ __forceinline__ float lrelu(float x) {
    return fmaxf(x, 0.0f) + 0.01f * fminf(x, 0.0f);
}
static __device__ __forceinline__ float rfl(float x) {
    return __int_as_float(__builtin_amdgcn_readfirstlane(__float_as_int(x)));
}

// d_ws: double acc[20*NCOPY]; slots 0-9 = BN1 sum/sumsq, 10-19 = BN2 sum/sumsq.
// Cross-kernel visibility via kernel-boundary cache flush/invalidate.

// ==== K1: BN1 stats via separable per-node sums (d_ij = z_i * w_j) =========
__global__ __launch_bounds__(TPB) void stats1_kernel(
    const float* __restrict__ feat, const float* __restrict__ ang,
    const float* __restrict__ W1, const float* __restrict__ b1,
    double* __restrict__ acc)
{
    __shared__ double bacc[4][10];
    const int t = threadIdx.x;
    const int lane = t & 63;
    const int wv = t >> 6;

    float v0[5], v1[5], v2[5], v3[5], bb1[5];
#pragma unroll
    for (int o = 0; o < 5; ++o) {
        v0[o] = rfl(W1[o*5+0] - W1[o*5+2]);
        v1[o] = rfl(W1[o*5+1] + W1[o*5+2]);
        v2[o] = rfl(W1[o*5+3]);
        v3[o] = rfl(W1[o*5+4]);
        bb1[o] = rfl(b1[o]);
    }

    float f = 0.f, zr = 0.f, zi = 0.f, inv = 0.f;
    if (lane < PP) {
        const int idx = (blockIdx.x * 4 + wv) * PP + lane;
        f = feat[idx];
        float2 a2 = ((const float2*)ang)[idx];
        zr = a2.x; zi = a2.y;
        inv = 1.0f / (zr*zr + zi*zi);
    }
    const float wr = zr * inv, wi = -zi * inv;   // lanes >=50: all zero

    float p[16] = { f, f*f, zr, zi, wr, wi, f*zr, f*zi, f*wr, f*wi,
                    zr*zr, zi*zi, zr*zi, wr*wr, wi*wi, wr*wi };
#pragma unroll
    for (int k = 0; k < 16; ++k) {
        float v = p[k];
#pragma unroll
        for (int off = 32; off > 0; off >>= 1) v += __shfl_down(v, off, 64);
        p[k] = v;
    }
    if (lane == 0) {
        const double P0 = p[0], P1 = p[1], P2 = p[2], P3 = p[3], P4 = p[4];
        const double P5 = p[5], P6 = p[6], P7 = p[7], P8 = p[8], P9 = p[9];
        const double P10 = p[10], P11 = p[11], P12 = p[12];
        const double P13 = p[13], P14 = p[14], P15 = p[15];
        const double Sfi = 50.0 * P0;
        const double Sdr = P2*P4 - P3*P5;
        const double Sdi = P3*P4 + P2*P5;
        const double m00 = 50.0 * P1, m11 = m00, m01 = P0*P0;
        const double m02 = P6*P4 - P7*P5;
        const double m03 = P7*P4 + P6*P5;
        const double m12 = P2*P8 - P3*P9;
        const double m13 = P3*P8 + P2*P9;
        const double m22 = P10*P13 - 2.0*P12*P15 + P11*P14;
        const double m33 = P11*P13 + 2.0*P12*P15 + P10*P14;
        const double m23 = P12*P13 + P10*P15 - P11*P15 - P12*P14;
#pragma unroll
        for (int o = 0; o < 5; ++o) {
            const double a0=v0[o], a1=v1[o], a2=v2[o], a3=v3[o], bo=bb1[o];
            const double sy = a0*Sfi + a1*Sfi + a2*Sdr + a3*Sdi + 2500.0*bo;
            const double q  = a0*a0*m00 + a1*a1*m11 + a2*a2*m22 + a3*a3*m33
                           + 2.0*(a0*a1*m01 + a0*a2*m02 + a0*a3*m03
                                + a1*a2*m12 + a1*a3*m13 + a2*a3*m23);
            bacc[wv][o]   = sy;
            bacc[wv][5+o] = q + 2.0*bo*sy - 2500.0*bo*bo;
        }
    }
    __syncthreads();
    if (t < 10) {
        double s = bacc[0][t] + bacc[1][t] + bacc[2][t] + bacc[3][t];
        atomicAdd(&acc[t * NCOPY + (blockIdx.x & (NCOPY-1))], s);
    }
}

// ==== K2: edge sweep: h1 = lrelu(BN1(y1)); y2 sums -> BN2 stats ============
__global__ __launch_bounds__(TPB, 2) void pass2_kernel(
    const float* __restrict__ feat, const float* __restrict__ ang,
    const float* __restrict__ W1, const float* __restrict__ b1,
    const float* __restrict__ g1, const float* __restrict__ bt1,
    const float* __restrict__ W2, const float* __restrict__ b2,
    double* __restrict__ acc)
{
    __shared__ float4 nd[GB * PP];
    __shared__ double tmp[10];
    __shared__ float red[4][10];
    const int t = threadIdx.x;

    if (t < GB * PP) {
        // flat coalesced staging: one 400B stream instead of two 50-lane segments
        const int idx = blockIdx.x * (GB * PP) + t;
        float f = feat[idx];
        float2 a2 = ((const float2*)ang)[idx];
        nd[t] = make_float4(f, a2.x, a2.y, 1.0f / (a2.x*a2.x + a2.y*a2.y));
    } else if (t >= 128 && t < 138) {
        const int k = t - 128;
        double s = 0.0;
#pragma unroll
        for (int c = 0; c < NCOPY; ++c) s += acc[k * NCOPY + c];
        tmp[k] = s;
    }

    float v0[5], v1[5], v2[5], v3[5], bb1[5], w2[25], bb2[5];
#pragma unroll
    for (int o = 0; o < 5; ++o) {
        v0[o] = rfl(W1[o*5+0] - W1[o*5+2]);
        v1[o] = rfl(W1[o*5+1] + W1[o*5+2]);
        v2[o] = rfl(W1[o*5+3]);
        v3[o] = rfl(W1[o*5+4]);
        bb1[o] = rfl(b1[o]); bb2[o] = rfl(b2[o]);
    }
#pragma unroll
    for (int i = 0; i < 25; ++i) w2[i] = rfl(W2[i]);

    __syncthreads();

    float sc1[5], sh1[5];
#pragma unroll
    for (int o = 0; o < 5; ++o) {
        double mu  = tmp[o]   * INV_ETOT;
        double var = tmp[5+o] * INV_ETOT - mu * mu;
        float sc = rfl(g1[o]) * rsqrtf((float)var + EPSF);
        sc1[o] = rfl(sc);
        sh1[o] = rfl(rfl(bt1[o]) - (float)mu * sc);
    }

    float a[10];
#pragma unroll
    for (int k = 0; k < 10; ++k) a[k] = 0.f;

    if (t < 250) {
        const int pi = t / 5;
        const int s5 = t - pi*5;
#pragma unroll
        for (int g = 0; g < GB; ++g) {
            const float4 ni = nd[g*PP + pi];
            const float fi = ni.x, ari = ni.y, aii = ni.z;
            float4 njs[10];
#pragma unroll
            for (int q = 0; q < 10; ++q) njs[q] = nd[g*PP + s5*10 + q];
#pragma unroll
            for (int q = 0; q < 10; ++q) {
                const float4 nj = njs[q];
                const float dr = fmaf(ari, nj.y,  aii*nj.z) * nj.w;
                const float di = fmaf(aii, nj.y, -ari*nj.z) * nj.w;
                float h1[5];
#pragma unroll
                for (int o = 0; o < 5; ++o) {
                    float y = fmaf(v0[o], fi, fmaf(v1[o], nj.x,
                              fmaf(v2[o], dr, fmaf(v3[o], di, bb1[o]))));
                    h1[o] = lrelu(fmaf(y, sc1[o], sh1[o]));
                }
#pragma unroll
                for (int o = 0; o < 5; ++o) {
                    float y = bb2[o];
                    y = fmaf(w2[o*5+0], h1[0], y);
                    y = fmaf(w2[o*5+1], h1[1], y);
                    y = fmaf(w2[o*5+2], h1[2], y);
                    y = fmaf(w2[o*5+3], h1[3], y);
                    y = fmaf(w2[o*5+4], h1[4], y);
                    a[o]   += y;
                    a[5+o]  = fmaf(y, y, a[5+o]);
                }
            }
        }
    }

#pragma unroll
    for (int k = 0; k < 10; ++k) {
        float v = a[k];
#pragma unroll
        for (int off = 32; off > 0; off >>= 1) v += __shfl_down(v, off, 64);
        a[k] = v;
    }
    const int lane = t & 63, wv = t >> 6;
    if (lane == 0) {
#pragma unroll
        for (int k = 0; k < 10; ++k) red[wv][k] = a[k];
    }
    __syncthreads();
    if (t < 10) {
        atomicAdd(&acc[(10 + t) * NCOPY + (blockIdx.x & (NCOPY-1))],
                  (double)(red[0][t] + red[1][t] + red[2][t] + red[3][t]));
    }
}

// ==== K3: full MLP, mean-aggregate per dst, rotate, write ==================
__global__ __launch_bounds__(TPB, 2) void pass3_kernel(
    const float* __restrict__ pt,
    const float* __restrict__ feat, const float* __restrict__ ang,
    const float* __restrict__ W1, const float* __restrict__ b1,
    const float* __restrict__ g1, const float* __restrict__ bt1,
    const float* __restrict__ W2, const float* __restrict__ b2,
    const float* __restrict__ g2, const float* __restrict__ bt2,
    const float* __restrict__ W3, const float* __restrict__ b3,
    const double* __restrict__ acc, float* __restrict__ out)
{
    __shared__ float4 nd[GB * PP];
    __shared__ float spt[GB * PP];
    __shared__ double tmp[20];
    __shared__ float part[250][5];
    const int t = threadIdx.x;

    if (t < GB * PP) {
        const int idx = blockIdx.x * (GB * PP) + t;
        float f = feat[idx];
        float2 a2 = ((const float2*)ang)[idx];
        nd[t] = make_float4(f, a2.x, a2.y, 1.0f / (a2.x*a2.x + a2.y*a2.y));
        spt[t] = pt[idx];
    } else if (t >= 128 && t < 148) {
        const int k = t - 128;
        double s = 0.0;
#pragma unroll
        for (int c = 0; c < NCOPY; ++c) s += acc[k * NCOPY + c];
        tmp[k] = s;
    }

    float v0[5], v1[5], v2[5], v3[5], bb1[5], w2[25], bb2[5], w3[25], bb3[5];
#pragma unroll
    for (int o = 0; o < 5; ++o) {
        v0[o] = rfl(W1[o*5+0] - W1[o*5+2]);
        v1[o] = rfl(W1[o*5+1] + W1[o*5+2]);
        v2[o] = rfl(W1[o*5+3]);
        v3[o] = rfl(W1[o*5+4]);
        bb1[o] = rfl(b1[o]); bb2[o] = rfl(b2[o]); bb3[o] = rfl(b3[o]);
    }
#pragma unroll
    for (int i = 0; i < 25; ++i) { w2[i] = rfl(W2[i]); w3[i] = rfl(W3[i]); }

    __syncthreads();

    float sc1[5], sh1[5], sc2[5], sh2[5];
#pragma unroll
    for (int o = 0; o < 5; ++o) {
        double mu1  = tmp[o]    * INV_ETOT;
        double var1 = tmp[5+o]  * INV_ETOT - mu1 * mu1;
        float s1 = rfl(g1[o]) * rsqrtf((float)var1 + EPSF);
        sc1[o] = rfl(s1);
        sh1[o] = rfl(rfl(bt1[o]) - (float)mu1 * s1);
        double mu2  = tmp[10+o] * INV_ETOT;
        double var2 = tmp[15+o] * INV_ETOT - mu2 * mu2;
        float s2 = rfl(g2[o]) * rsqrtf((float)var2 + EPSF);
        sc2[o] = rfl(s2);
        sh2[o] = rfl(rfl(bt2[o]) - (float)mu2 * s2);
    }

    const int pi = t / 5;
    const int s5 = t - pi*5;

#pragma unroll
    for (int g = 0; g < GB; ++g) {
        float a[5] = {0.f, 0.f, 0.f, 0.f, 0.f};
        if (t < 250) {
            const float4 ni = nd[g*PP + pi];
            const float fi = ni.x, ari = ni.y, aii = ni.z;
            float4 njs[10];
#pragma unroll
            for (int q = 0; q < 10; ++q) njs[q] = nd[g*PP + s5*10 + q];
#pragma unroll
            for (int q = 0; q < 10; ++q) {
                const float4 nj = njs[q];
                const float dr = fmaf(ari, nj.y,  aii*nj.z) * nj.w;
                const float di = fmaf(aii, nj.y, -ari*nj.z) * nj.w;
                float h1[5], h2[5];
#pragma unroll
                for (int o = 0; o < 5; ++o) {
                    float y = fmaf(v0[o], fi, fmaf(v1[o], nj.x,
                              fmaf(v2[o], dr, fmaf(v3[o], di, bb1[o]))));
                    h1[o] = lrelu(fmaf(y, sc1[o], sh1[o]));
                }
#pragma unroll
                for (int o = 0; o < 5; ++o) {
                    float y = bb2[o];
                    y = fmaf(w2[o*5+0], h1[0], y);
                    y = fmaf(w2[o*5+1], h1[1], y);
                    y = fmaf(w2[o*5+2], h1[2], y);
                    y = fmaf(w2[o*5+3], h1[3], y);
                    y = fmaf(w2[o*5+4], h1[4], y);
                    h2[o] = lrelu(fmaf(y, sc2[o], sh2[o]));
                }
#pragma unroll
                for (int o = 0; o < 5; ++o) {
                    float y = bb3[o];
                    y = fmaf(w3[o*5+0], h2[0], y);
                    y = fmaf(w3[o*5+1], h2[1], y);
                    y = fmaf(w3[o*5+2], h2[2], y);
                    y = fmaf(w3[o*5+3], h2[3], y);
                    y = fmaf(w3[o*5+4], h2[4], y);
                    a[o] += y;
                }
            }
#pragma unroll
            for (int c = 0; c < 5; ++c) part[t][c] = a[c];
        }
        __syncthreads();

        if (t < PP) {
            float m[5];
#pragma unroll
            for (int c = 0; c < 5; ++c) {
                m[c] = (part[5*t][c] + part[5*t+1][c] + part[5*t+2][c] +
                        part[5*t+3][c] + part[5*t+4][c]) * 0.02f;
            }
            const int node = g*PP + t;
            const int d = blockIdx.x * (GB * PP) + node;
            const float4 ni = nd[node];
            float ss, cc;
            sincosf(6.2831853071795865f * m[4], &ss, &cc);
            float* o = out + (size_t)d * 7;
            o[0] = spt[node];
            o[1] = m[0];
            o[2] = m[1];
            o[3] = m[2];
            o[4] = m[3];
            o[5] = cc * ni.y - ss * ni.z;
            o[6] = cc * ni.z + ss * ni.y;
        }
        __syncthreads();
    }
}

extern "C" void kernel_launch(void* const* d_in, const int* in_sizes, int n_in,
                              void* d_out, int out_size, void* d_ws, size_t ws_size,
                              hipStream_t stream)
{
    const float* pt   = (const float*)d_in[0];
    const float* feat = (const float*)d_in[1];
    const float* ang  = (const float*)d_in[2];
    const float* W1   = (const float*)d_in[3];
    const float* b1   = (const float*)d_in[4];
    const float* g1   = (const float*)d_in[5];
    const float* bt1  = (const float*)d_in[6];
    const float* W2   = (const float*)d_in[7];
    const float* b2   = (const float*)d_in[8];
    const float* g2   = (const float*)d_in[9];
    const float* bt2  = (const float*)d_in[10];
    const float* W3   = (const float*)d_in[11];
    const float* b3   = (const float*)d_in[12];
    // d_in[13] = edge_index: closed-form structure (dst=b*P+pi, src=b*P+pj), unused
    float* out = (float*)d_out;
    double* acc = (double*)d_ws;   // 20*NCOPY doubles

    hipMemsetAsync(d_ws, 0, 20 * NCOPY * sizeof(double), stream);
    stats1_kernel<<<NBLK1, TPB, 0, stream>>>(feat, ang, W1, b1, acc);
    pass2_kernel<<<NBLK2, TPB, 0, stream>>>(feat, ang, W1, b1, g1, bt1, W2, b2, acc);
    pass3_kernel<<<NBLK2, TPB, 0, stream>>>(pt, feat, ang, W1, b1, g1, bt1, W2, b2,
                                            g2, bt2, W3, b3, acc, out);
}